// Round 1
// baseline (381.166 us; speedup 1.0000x reference)
//
#include <hip/hip_runtime.h>

#define BB 16
#define NL 60
#define NA 3
#define NC 80

__device__ __constant__ float d_AW[9] = {12.f,19.f,40.f,36.f,76.f,72.f,142.f,192.f,459.f};
__device__ __constant__ float d_AH[9] = {16.f,36.f,28.f,75.f,55.f,146.f,110.f,243.f,401.f};

__device__ __forceinline__ float sigmoidf(float v){ return 1.0f/(1.0f + expf(-v)); }
__device__ __forceinline__ float bcef(float p, float t){
    float lp  = logf(fmaxf(p, 1e-12f));
    float l1p = log1pf(-fminf(p, 1.0f - 1e-7f));
    return -(t*lp + (1.0f - t)*l1p);
}

// ---------------- label prep: per (b,l) x 3 scales ----------------
__global__ __launch_bounds__(256) void prep_kernel(const float* __restrict__ labels,
        float* __restrict__ tb, int* __restrict__ code,
        float* __restrict__ tvals, double* __restrict__ acc)
{
    int idx = blockIdx.x*256 + threadIdx.x;
    if (blockIdx.x == 0 && threadIdx.x < 5) acc[threadIdx.x] = 0.0;
    if (idx >= BB*NL) return;
    const float* lb = labels + idx*5;
    float x1=lb[0], y1=lb[1], x2=lb[2], y2=lb[3], cl=lb[4];
    bool valid = (x1+y1+x2+y2+cl) > 0.0f;
    const int   Fs[3] = {76,38,19};
    const float Ss[3] = {8.f,16.f,32.f};
    for (int s=0; s<3; s++){
        float st = Ss[s]; int F = Fs[s];
        float tx = (x1+x2)/(2.0f*st);
        float ty = (y1+y2)/(2.0f*st);
        float tw = (x2-x1)/st;
        float th = (y2-y1)/st;
        float at = tw*th;
        float best = -1.0f; int bi = 0;
        for (int k=0; k<9; k++){
            float rw = d_AW[k]/st, rh = d_AH[k]/st;
            float mw = fminf(tw,rw), mh = fminf(th,rh);
            float inter = (mw>0.f && mh>0.f) ? mw*mh : 0.f;
            float aiou = inter/(at + rw*rh - inter);
            if (aiou > best){ best = aiou; bi = k; }   // first-max tie-break = argmax
        }
        int bn = bi % 3;
        bool use = valid && (bi/3 == s);
        int ii = (int)tx, jj = (int)ty;
        int o = s*(BB*NL) + idx;
        tb[o*4+0]=tx; tb[o*4+1]=ty; tb[o*4+2]=tw; tb[o*4+3]=th;
        int cell = (bn*F + jj)*F + ii;
        code[o] = use ? (cell | (((int)cl) << 20)) : -1;
        float aw = d_AW[s*3+bn]/st, ah = d_AH[s*3+bn]/st;
        tvals[o*6+0] = tx - (float)ii;
        tvals[o*6+1] = ty - (float)jj;
        tvals[o*6+2] = logf(tw/aw + 1e-16f);
        tvals[o*6+3] = logf(th/ah + 1e-16f);
        tvals[o*6+4] = sqrtf(2.0f - tw*th/((float)F*(float)F));
        tvals[o*6+5] = cl;
    }
}

// ---------------- main per-cell kernel ----------------
template<int SID>
__global__ __launch_bounds__(256) void main_kernel(const float* __restrict__ raw,
        const float* __restrict__ tb, const int* __restrict__ code,
        const float* __restrict__ tvals, double* __restrict__ acc)
{
    constexpr int   F  = (SID==0)?76:(SID==1)?38:19;
    constexpr float ST = (SID==0)?8.f:(SID==1)?16.f:32.f;
    constexpr int   FF = F*F;
    __shared__ float s_tb[NL][4];
    __shared__ int   s_code[NL];
    __shared__ float red[5][4];

    int tid = threadIdx.x;
    int b   = blockIdx.y;
    {
        int base = (SID*BB + b)*NL;
        if (tid < NL){
            const float* p = tb + (base + tid)*4;
            s_tb[tid][0]=p[0]; s_tb[tid][1]=p[1]; s_tb[tid][2]=p[2]; s_tb[tid][3]=p[3];
            s_code[tid] = code[base + tid];
        }
    }
    __syncthreads();

    int cell = blockIdx.x*256 + tid;
    float lxy=0.f, lwh=0.f, lob=0.f, lcl=0.f, l2=0.f;
    if (cell < NA*FF){
        int a   = cell / FF;
        int rem = cell - a*FF;
        int j   = rem / F;
        int i   = rem - j*F;
        const float* base = raw + (size_t)(b*(NA*(5+NC)) + a*(5+NC))*FF + rem;
        float c0 = base[0*FF], c1 = base[1*FF], c2 = base[2*FF], c3 = base[3*FF], c4 = base[4*FF];
        float x = sigmoidf(c0), y = sigmoidf(c1), obj = sigmoidf(c4);
        float aw = d_AW[SID*3+a]/ST, ah = d_AH[SID*3+a]/ST;
        float pw = expf(c2)*aw, ph = expf(c3)*ah;
        float px = x + (float)i, py = y + (float)j;
        float hx = 0.5f*pw, hy = 0.5f*ph;
        float plox = px-hx, phix = px+hx, ploy = py-hy, phiy = py+hy;
        float ap = pw*ph;
        float maxiou = 0.0f;
        int tgt = -1;
        unsigned long long cm0=0ull, cm1=0ull;   // class multi-hot (collision-correct)
        for (int l=0; l<NL; l++){
            float tx=s_tb[l][0], ty=s_tb[l][1], tw=s_tb[l][2], th=s_tb[l][3];
            float htw=0.5f*tw, hth=0.5f*th;
            float tlx = fmaxf(plox, tx-htw);
            float brx = fminf(phix, tx+htw);
            float tly = fmaxf(ploy, ty-hth);
            float bry = fminf(phiy, ty+hth);
            float iw = brx-tlx, ih = bry-tly;
            float ai = (iw>0.f && ih>0.f) ? iw*ih : 0.f;
            float iou = ai/(ap + tw*th - ai);
            maxiou = fmaxf(maxiou, iou);
            int cd = s_code[l];
            if (cd >= 0 && (cd & 0xFFFFF) == cell){
                tgt = l;                               // last writer wins (np semantics)
                int cc = cd >> 20;
                if (cc < 64) cm0 |= 1ull<<cc; else cm1 |= 1ull<<(cc-64);
            }
        }
        if (tgt >= 0){
            const float* tv = tvals + ((size_t)(SID*BB + b)*NL + tgt)*6;
            float t0=tv[0], t1=tv[1], t2=tv[2], t3=tv[3], sc=tv[4];
            float w2 = sc*sc;
            lxy = w2*(bcef(x,t0) + bcef(y,t1));
            float d0 = (c2 - t2)*sc, d1 = (c3 - t3)*sc;
            lwh = 0.5f*(d0*d0 + d1*d1);
            lob = -logf(fmaxf(obj, 1e-12f));
            float dx = x-t0, dy = y-t1, dob = obj-1.0f;
            l2 = dx*dx + dy*dy + d0*d0 + d1*d1 + dob*dob;
            for (int c=0; c<NC; c++){
                float p = sigmoidf(base[(5+c)*FF]);
                bool hot = (c < 64) ? ((cm0>>c)&1ull) : ((cm1>>(c-64))&1ull);
                float t = hot ? 1.0f : 0.0f;
                lcl += bcef(p, t);
                float d = p - t; l2 += d*d;
            }
        } else if (maxiou <= 0.5f){
            lob = -log1pf(-fminf(obj, 1.0f - 1e-7f));
            l2  = obj*obj;
        }
    }

    // block reduce 5 components: wave shuffle -> LDS -> one atomic per component
    float v0=lxy, v1=lwh, v2=lob, v3=lcl, v4=l2;
    #pragma unroll
    for (int off=32; off>0; off>>=1){
        v0 += __shfl_down(v0, off, 64);
        v1 += __shfl_down(v1, off, 64);
        v2 += __shfl_down(v2, off, 64);
        v3 += __shfl_down(v3, off, 64);
        v4 += __shfl_down(v4, off, 64);
    }
    if ((tid & 63) == 0){
        int w = tid >> 6;
        red[0][w]=v0; red[1][w]=v1; red[2][w]=v2; red[3][w]=v3; red[4][w]=v4;
    }
    __syncthreads();
    if (tid == 0){
        #pragma unroll
        for (int c=0; c<5; c++){
            atomicAdd(&acc[c], (double)(red[c][0]+red[c][1]+red[c][2]+red[c][3]));
        }
    }
}

__global__ void fin_kernel(const double* __restrict__ acc, float* __restrict__ out){
    if (threadIdx.x == 0 && blockIdx.x == 0){
        double lxy=acc[0], lwh=acc[1], lob=acc[2], lcl=acc[3], l2=acc[4];
        out[0]=(float)(lxy+lwh+lob+lcl);
        out[1]=(float)lxy; out[2]=(float)lwh; out[3]=(float)lob;
        out[4]=(float)lcl; out[5]=(float)l2;
    }
}

extern "C" void kernel_launch(void* const* d_in, const int* in_sizes, int n_in,
                              void* d_out, int out_size, void* d_ws, size_t ws_size,
                              hipStream_t stream) {
    const float* x0     = (const float*)d_in[0];
    const float* x1     = (const float*)d_in[1];
    const float* x2     = (const float*)d_in[2];
    const float* labels = (const float*)d_in[3];
    float* out = (float*)d_out;

    char* ws = (char*)d_ws;
    double* acc  = (double*)ws;                         // 5 doubles (reserve 64 B)
    float*  tb   = (float*)(ws + 64);                   // 3*960*4 floats = 46080 B
    int*    code = (int*)(ws + 64 + 46080);             // 3*960 ints    = 11520 B
    float*  tvals= (float*)(ws + 64 + 46080 + 11520);   // 3*960*6 floats= 69120 B

    prep_kernel<<<dim3((BB*NL + 255)/256), 256, 0, stream>>>(labels, tb, code, tvals, acc);

    main_kernel<0><<<dim3((NA*76*76 + 255)/256, BB), 256, 0, stream>>>(x0, tb, code, tvals, acc);
    main_kernel<1><<<dim3((NA*38*38 + 255)/256, BB), 256, 0, stream>>>(x1, tb, code, tvals, acc);
    main_kernel<2><<<dim3((NA*19*19 + 255)/256, BB), 256, 0, stream>>>(x2, tb, code, tvals, acc);

    fin_kernel<<<1, 64, 0, stream>>>(acc, out);
}

// Round 2
// 140.495 us; speedup vs baseline: 2.7130x; 2.7130x over previous
//
#include <hip/hip_runtime.h>

#define BB 16
#define NL 60
#define NA 3
#define NC 80

// block counts per scale (compile-time, must match launch grids)
#define NBX0 68   // ceil(3*76*76/256)
#define NBX1 17   // ceil(3*38*38/256)
#define NBX2 5    // ceil(3*19*19/256)
#define NBLK0 (NBX0*BB)
#define NBLK1 (NBX1*BB)
#define NBLK2 (NBX2*BB)
#define NBLKT (NBLK0+NBLK1+NBLK2)   // 1440

__device__ __constant__ float d_AW[9] = {12.f,19.f,40.f,36.f,76.f,72.f,142.f,192.f,459.f};
__device__ __constant__ float d_AH[9] = {16.f,36.f,28.f,75.f,55.f,146.f,110.f,243.f,401.f};

__device__ __forceinline__ float sig_pos(float v){            // sigmoid(v)
    return __fdividef(1.0f, 1.0f + __expf(-v));
}
__device__ __forceinline__ float sig_neg(float v){            // sigmoid(-v) == 1 - sigmoid(v)
    return __fdividef(1.0f, 1.0f + __expf(v));
}
__device__ __forceinline__ float bcef(float p, float t){      // targets only (rare)
    float lp  = __logf(fmaxf(p, 1e-12f));
    float l1p = __logf(1.0f - fminf(p, 1.0f - 1e-7f));
    return -(t*lp + (1.0f - t)*l1p);
}

// ---------------- label prep: per (b,l) x 3 scales ----------------
__global__ __launch_bounds__(256) void prep_kernel(const float* __restrict__ labels,
        float4* __restrict__ bx, float* __restrict__ area,
        int* __restrict__ code, float* __restrict__ tvals)
{
    int idx = blockIdx.x*256 + threadIdx.x;
    if (idx >= BB*NL) return;
    const float* lb = labels + idx*5;
    float x1=lb[0], y1=lb[1], x2=lb[2], y2=lb[3], cl=lb[4];
    bool valid = (x1+y1+x2+y2+cl) > 0.0f;
    const int   Fs[3] = {76,38,19};
    const float Ss[3] = {8.f,16.f,32.f};
    for (int s=0; s<3; s++){
        float st = Ss[s]; int F = Fs[s];
        float tx = (x1+x2)/(2.0f*st);
        float ty = (y1+y2)/(2.0f*st);
        float tw = (x2-x1)/st;
        float th = (y2-y1)/st;
        float at = tw*th;
        float best = -1.0f; int bi = 0;
        for (int k=0; k<9; k++){
            float rw = d_AW[k]/st, rh = d_AH[k]/st;
            float mw = fminf(tw,rw), mh = fminf(th,rh);
            float inter = (mw>0.f && mh>0.f) ? mw*mh : 0.f;
            float aiou = inter/(at + rw*rh - inter);
            if (aiou > best){ best = aiou; bi = k; }   // first-max tie-break = argmax
        }
        int bn = bi % 3;
        bool use = valid && (bi/3 == s);
        int ii = (int)tx, jj = (int)ty;
        int o = s*(BB*NL) + idx;
        float htw = 0.5f*tw, hth = 0.5f*th;
        bx[o]   = make_float4(tx-htw, tx+htw, ty-hth, ty+hth);
        area[o] = at;
        int cell = (bn*F + jj)*F + ii;
        code[o] = use ? (cell | (((int)cl) << 20)) : -1;
        float aw = d_AW[s*3+bn]/st, ah = d_AH[s*3+bn]/st;
        tvals[o*6+0] = tx - (float)ii;
        tvals[o*6+1] = ty - (float)jj;
        tvals[o*6+2] = logf(tw/aw + 1e-16f);
        tvals[o*6+3] = logf(th/ah + 1e-16f);
        tvals[o*6+4] = sqrtf(2.0f - tw*th/((float)F*(float)F));
        tvals[o*6+5] = cl;
    }
}

// ---------------- main per-cell kernel ----------------
template<int SID>
__global__ __launch_bounds__(256) void main_kernel(const float* __restrict__ raw,
        const float4* __restrict__ bx, const float* __restrict__ area,
        const int* __restrict__ code, const float* __restrict__ tvals,
        float* __restrict__ part, int slot_base)
{
    constexpr int   F  = (SID==0)?76:(SID==1)?38:19;
    constexpr float ST = (SID==0)?8.f:(SID==1)?16.f:32.f;
    constexpr int   FF = F*F;
    __shared__ float4 s_bx[NL];
    __shared__ float  s_ar[NL];
    __shared__ int    s_code[NL];
    __shared__ float  red[5][4];

    int tid = threadIdx.x;
    int b   = blockIdx.y;
    {
        int base = (SID*BB + b)*NL;
        if (tid < NL){
            s_bx[tid]   = bx[base + tid];
            s_ar[tid]   = area[base + tid];
            s_code[tid] = code[base + tid];
        }
    }
    __syncthreads();

    int cell = blockIdx.x*256 + tid;
    float lxy=0.f, lwh=0.f, lob=0.f, lcl=0.f, l2=0.f;
    if (cell < NA*FF){
        int a   = cell / FF;
        int rem = cell - a*FF;
        int j   = rem / F;
        int i   = rem - j*F;
        const float* base = raw + (size_t)(b*(NA*(5+NC)) + a*(5+NC))*FF + rem;
        float c0 = base[0*FF], c1 = base[1*FF], c2 = base[2*FF], c3 = base[3*FF], c4 = base[4*FF];
        float x   = sig_pos(c0), y = sig_pos(c1);
        float snb = sig_neg(c4);          // 1 - obj, computed stably from logit
        float obj = 1.0f - snb;
        float aw = d_AW[SID*3+a]/ST, ah = d_AH[SID*3+a]/ST;
        float pw = __expf(c2)*aw, ph = __expf(c3)*ah;
        float px = x + (float)i, py = y + (float)j;
        float hx = 0.5f*pw, hy = 0.5f*ph;
        float plox = px-hx, phix = px+hx, ploy = py-hy, phiy = py+hy;
        float ap = pw*ph;
        float maxiou = 0.0f;
        int tgt = -1;
        unsigned long long cm0=0ull, cm1=0ull;   // class multi-hot (collision-correct)
        for (int l=0; l<NL; l++){
            float4 bb = s_bx[l];
            float tlx = fmaxf(plox, bb.x);
            float brx = fminf(phix, bb.y);
            float tly = fmaxf(ploy, bb.z);
            float bry = fminf(phiy, bb.w);
            float iw = brx-tlx, ih = bry-tly;
            float ai = (iw>0.f && ih>0.f) ? iw*ih : 0.f;
            float at = s_ar[l];
            float iou = __fdividef(ai, ap + at - ai);
            maxiou = fmaxf(maxiou, iou);
            int cd = s_code[l];
            if (cd >= 0 && (cd & 0xFFFFF) == cell){
                tgt = l;                               // last writer wins (np semantics)
                int cc = cd >> 20;
                if (cc < 64) cm0 |= 1ull<<cc; else cm1 |= 1ull<<(cc-64);
            }
        }
        if (tgt >= 0){
            const float* tv = tvals + ((size_t)(SID*BB + b)*NL + tgt)*6;
            float t0=tv[0], t1=tv[1], t2=tv[2], t3=tv[3], sc=tv[4];
            float w2 = sc*sc;
            lxy = w2*(bcef(x,t0) + bcef(y,t1));
            float d0 = (c2 - t2)*sc, d1 = (c3 - t3)*sc;
            lwh = 0.5f*(d0*d0 + d1*d1);
            lob = -__logf(fmaxf(obj, 1e-12f));
            float dx = x-t0, dy = y-t1, dob = obj-1.0f;
            l2 = dx*dx + dy*dy + d0*d0 + d1*d1 + dob*dob;
            for (int c=0; c<NC; c++){
                float p = sig_pos(base[(5+c)*FF]);
                bool hot = (c < 64) ? ((cm0>>c)&1ull) : ((cm1>>(c-64))&1ull);
                float t = hot ? 1.0f : 0.0f;
                lcl += bcef(p, t);
                float d = p - t; l2 += d*d;
            }
        } else if (maxiou <= 0.5f){
            // -log1p(-min(obj,1-1e-7)) == -log(max(1-obj,1e-7)), 1-obj from logit
            lob = -__logf(fmaxf(snb, 1e-7f));
            l2  = obj*obj;
        }
    }

    // block reduce 5 components: wave shuffle -> LDS -> ONE partial write per block
    float v0=lxy, v1=lwh, v2=lob, v3=lcl, v4=l2;
    #pragma unroll
    for (int off=32; off>0; off>>=1){
        v0 += __shfl_down(v0, off, 64);
        v1 += __shfl_down(v1, off, 64);
        v2 += __shfl_down(v2, off, 64);
        v3 += __shfl_down(v3, off, 64);
        v4 += __shfl_down(v4, off, 64);
    }
    if ((tid & 63) == 0){
        int w = tid >> 6;
        red[0][w]=v0; red[1][w]=v1; red[2][w]=v2; red[3][w]=v3; red[4][w]=v4;
    }
    __syncthreads();
    if (tid == 0){
        int slot = slot_base + blockIdx.y*gridDim.x + blockIdx.x;
        #pragma unroll
        for (int c=0; c<5; c++){
            part[c*NBLKT + slot] = red[c][0]+red[c][1]+red[c][2]+red[c][3];
        }
    }
}

// ---------------- final reduction: 1440 partials x 5 comps ----------------
__global__ __launch_bounds__(256) void fin_kernel(const float* __restrict__ part,
                                                  float* __restrict__ out)
{
    __shared__ double red[5][4];
    int tid = threadIdx.x;
    double v[5] = {0,0,0,0,0};
    for (int i = tid; i < NBLKT; i += 256){
        #pragma unroll
        for (int c=0; c<5; c++) v[c] += (double)part[c*NBLKT + i];
    }
    #pragma unroll
    for (int off=32; off>0; off>>=1){
        #pragma unroll
        for (int c=0; c<5; c++) v[c] += __shfl_down(v[c], off, 64);
    }
    if ((tid & 63) == 0){
        int w = tid >> 6;
        #pragma unroll
        for (int c=0; c<5; c++) red[c][w] = v[c];
    }
    __syncthreads();
    if (tid == 0){
        double lxy = red[0][0]+red[0][1]+red[0][2]+red[0][3];
        double lwh = red[1][0]+red[1][1]+red[1][2]+red[1][3];
        double lob = red[2][0]+red[2][1]+red[2][2]+red[2][3];
        double lcl = red[3][0]+red[3][1]+red[3][2]+red[3][3];
        double l2  = red[4][0]+red[4][1]+red[4][2]+red[4][3];
        out[0]=(float)(lxy+lwh+lob+lcl);
        out[1]=(float)lxy; out[2]=(float)lwh; out[3]=(float)lob;
        out[4]=(float)lcl; out[5]=(float)l2;
    }
}

extern "C" void kernel_launch(void* const* d_in, const int* in_sizes, int n_in,
                              void* d_out, int out_size, void* d_ws, size_t ws_size,
                              hipStream_t stream) {
    const float* x0     = (const float*)d_in[0];
    const float* x1     = (const float*)d_in[1];
    const float* x2     = (const float*)d_in[2];
    const float* labels = (const float*)d_in[3];
    float* out = (float*)d_out;

    // workspace layout (16B-aligned chunks)
    char* ws = (char*)d_ws;
    float*  part  = (float*)ws;                      // 5*1440*4   = 28800 B
    float4* bx    = (float4*)(ws + 28800);           // 3*960*16   = 46080 B
    float*  area  = (float*)(ws + 28800 + 46080);    // 3*960*4    = 11520 B
    int*    code  = (int*)(ws + 28800 + 46080 + 11520);            // 11520 B
    float*  tvals = (float*)(ws + 28800 + 46080 + 11520 + 11520);  // 3*960*24 = 69120 B

    prep_kernel<<<dim3((BB*NL + 255)/256), 256, 0, stream>>>(labels, bx, area, code, tvals);

    main_kernel<0><<<dim3(NBX0, BB), 256, 0, stream>>>(x0, bx, area, code, tvals, part, 0);
    main_kernel<1><<<dim3(NBX1, BB), 256, 0, stream>>>(x1, bx, area, code, tvals, part, NBLK0);
    main_kernel<2><<<dim3(NBX2, BB), 256, 0, stream>>>(x2, bx, area, code, tvals, part, NBLK0+NBLK1);

    fin_kernel<<<1, 256, 0, stream>>>(part, out);
}

// Round 3
// 68.961 us; speedup vs baseline: 5.5273x; 2.0373x over previous
//
#include <hip/hip_runtime.h>

#define BB 16
#define NL 60
#define NA 3
#define NC 80

// cell-pass blocks per batch: 68(s0)+17(s1)+5(s2), +3 target-pass blocks
#define NBX0 68
#define NBX1 17
#define NBX2 5
#define NBXC (NBX0+NBX1+NBX2)   // 90
#define NBX  (NBXC+3)           // 93
#define NBLKT (NBX*BB)          // 1488

__device__ __constant__ float d_AW[9] = {12.f,19.f,40.f,36.f,76.f,72.f,142.f,192.f,459.f};
__device__ __constant__ float d_AH[9] = {16.f,36.f,28.f,75.f,55.f,146.f,110.f,243.f,401.f};

__device__ __forceinline__ float sig_pos(float v){ return __fdividef(1.0f, 1.0f + __expf(-v)); }
__device__ __forceinline__ float sig_neg(float v){ return __fdividef(1.0f, 1.0f + __expf(v)); }
__device__ __forceinline__ float bcef(float p, float t){
    float lp  = __logf(fmaxf(p, 1e-12f));
    float l1p = __logf(1.0f - fminf(p, 1.0f - 1e-7f));
    return -(t*lp + (1.0f - t)*l1p);
}

__global__ __launch_bounds__(256) void fused_kernel(
        const float* __restrict__ x0, const float* __restrict__ x1,
        const float* __restrict__ x2, const float* __restrict__ labels,
        float* __restrict__ part)
{
    __shared__ float4 s_bx[NL];      // label box corners (lox,hix,loy,hiy)
    __shared__ float  s_at3[NL];     // label area / 3
    __shared__ int    s_code[NL];    // cell | class<<20, or -1
    __shared__ float  s_tv[NL][5];   // t0,t1,t2,t3,sc
    __shared__ int    s_used[NL];    // compacted used-cell codes
    __shared__ int    s_nuse;
    __shared__ float  red[5][4];

    const int tid = threadIdx.x;
    const int bxi = blockIdx.x;
    const int b   = blockIdx.y;

    int sid, xoff, tgtblk;
    if (bxi < NBX0)            { sid = 0; xoff = bxi;             tgtblk = 0; }
    else if (bxi < NBX0+NBX1)  { sid = 1; xoff = bxi-NBX0;        tgtblk = 0; }
    else if (bxi < NBXC)       { sid = 2; xoff = bxi-(NBX0+NBX1); tgtblk = 0; }
    else                       { sid = bxi-NBXC; xoff = 0;        tgtblk = 1; }

    const int   F  = (sid==0)?76:(sid==1)?38:19;
    const int   FF = F*F;
    const float ST = (sid==0)?8.f:(sid==1)?16.f:32.f;
    const float* raw = (sid==0)?x0:(sid==1)?x1:x2;

    // ---- cell pass: issue channel loads EARLY (overlap with prep+barrier) ----
    float c0=0.f,c1=0.f,c2=0.f,c3=0.f,c4=0.f;
    int cell=0, ca=0, ci=0, cj=0;
    bool active=false;
    if (!tgtblk){
        cell = xoff*256 + tid;
        if (cell < NA*FF){
            active = true;
            ca = cell/FF; int rem = cell - ca*FF; cj = rem/F; ci = rem - cj*F;
            const float* cb = raw + ((size_t)(b*(NA*(5+NC)) + ca*(5+NC)))*FF + rem;
            c0 = cb[0];
            c1 = cb[(size_t)FF];
            c2 = cb[(size_t)2*FF];
            c3 = cb[(size_t)3*FF];
            c4 = cb[(size_t)4*FF];
        }
    }

    if (tid == 0) s_nuse = 0;
    __syncthreads();

    // ---- per-block label prep into LDS (this block's scale only) ----
    if (tid < NL){
        const float* lb = labels + ((size_t)b*NL + tid)*5;
        float x1f=lb[0], y1f=lb[1], x2f=lb[2], y2f=lb[3], cl=lb[4];
        bool valid = (x1f+y1f+x2f+y2f+cl) > 0.0f;
        float tx=(x1f+x2f)/(2.0f*ST), ty=(y1f+y2f)/(2.0f*ST);
        float tw=(x2f-x1f)/ST, th=(y2f-y1f)/ST;
        float at=tw*th;
        float best=-1.0f; int bi=0;
        #pragma unroll
        for (int k=0;k<9;k++){
            float rw=d_AW[k]/ST, rh=d_AH[k]/ST;
            float mw=fminf(tw,rw), mh=fminf(th,rh);
            float inter=(mw>0.f && mh>0.f)? mw*mh : 0.f;
            float aiou = inter/(at + rw*rh - inter);
            if (aiou > best){ best=aiou; bi=k; }   // first-max = jnp.argmax
        }
        int bn = bi%3;
        bool use = valid && (bi/3 == sid);
        int ii=(int)tx, jj=(int)ty;
        float htw=0.5f*tw, hth=0.5f*th;
        s_bx[tid]  = make_float4(tx-htw, tx+htw, ty-hth, ty+hth);
        s_at3[tid] = at*(1.0f/3.0f);
        int cc = (bn*F + jj)*F + ii;
        s_code[tid] = use ? (cc | (((int)cl)<<20)) : -1;
        float aw=d_AW[sid*3+bn]/ST, ah=d_AH[sid*3+bn]/ST;
        s_tv[tid][0]=tx-(float)ii;
        s_tv[tid][1]=ty-(float)jj;
        s_tv[tid][2]=logf(tw/aw + 1e-16f);
        s_tv[tid][3]=logf(th/ah + 1e-16f);
        s_tv[tid][4]=sqrtf(2.0f - at/(float)FF);
        if (use){
            int p = atomicAdd(&s_nuse, 1);
            s_used[p] = cc;                       // order-independent (existence only)
        }
    }
    __syncthreads();

    float lxy=0.f, lwh=0.f, lob=0.f, lcl=0.f, l2=0.f;

    if (!tgtblk){
        if (active){
            float x=sig_pos(c0), y=sig_pos(c1);
            float aw=d_AW[sid*3+ca]/ST, ah=d_AH[sid*3+ca]/ST;
            float pw=__expf(c2)*aw, ph=__expf(c3)*ah;
            float px=x+(float)ci, py=y+(float)cj;
            float hx=0.5f*pw, hy=0.5f*ph;
            float plox=px-hx, phix=px+hx, ploy=py-hy, phiy=py+hy;
            float ap3=pw*ph*(1.0f/3.0f);
            // ignore flag: any IoU>0.5  <=>  ai > (ap+at)/3   (no divide, no running max)
            bool ign=false;
            #pragma unroll 4
            for (int l=0;l<NL;l++){
                float4 bb=s_bx[l];
                float tlx=fmaxf(plox,bb.x), brx=fminf(phix,bb.y);
                float tly=fmaxf(ploy,bb.z), bry=fminf(phiy,bb.w);
                float iw=brx-tlx, ih=bry-tly;
                ign = ign || ((fminf(iw,ih)>0.f) && (iw*ih > ap3+s_at3[l]));
            }
            // is this cell a target? (target losses handled by target blocks)
            bool ist=false;
            int n=s_nuse;
            for (int k=0;k<n;k++) ist = ist || (s_used[k]==cell);
            if (!ist && !ign){
                float snb=sig_neg(c4);            // 1-obj, stable from logit
                lob = -__logf(fmaxf(snb,1e-7f));  // == -log1p(-min(obj,1-1e-7))
                float obj=1.0f-snb;
                l2  = obj*obj;
            }
        }
    } else {
        // ---- target pass: all losses at target cells (xy, wh, obj, cls, l2) ----
        const int wv=tid>>6, lane=tid&63;
        for (int l=wv; l<NL; l+=4){               // wave-uniform
            int cd=s_code[l];
            if (cd<0) continue;
            int tcell = cd & 0xFFFFF;
            // last-writer + multi-hot class mask over all labels hitting this cell
            int last=-1; unsigned long long cm0=0ull, cm1=0ull;
            for (int q=0;q<NL;q++){
                int cq=s_code[q];
                if (cq>=0 && (cq&0xFFFFF)==tcell){
                    last=q; int cc=cq>>20;
                    if (cc<64) cm0|=1ull<<cc; else cm1|=1ull<<(cc-64);
                }
            }
            if (last!=l) continue;                // exactly one owner per cell
            int aa=tcell/FF, rr=tcell-aa*FF;
            const float* cb = raw + ((size_t)(b*(NA*(5+NC)) + aa*(5+NC)))*FF + rr;
            for (int c=lane; c<NC; c+=64){
                float p=sig_pos(cb[(size_t)(5+c)*FF]);
                bool hot=(c<64)? (((cm0>>c)&1ull)!=0ull) : (((cm1>>(c-64))&1ull)!=0ull);
                float t=hot?1.0f:0.0f;
                lcl += bcef(p,t);
                float d=p-t; l2+=d*d;
            }
            if (lane==0){
                float e0=cb[0], e1=cb[(size_t)FF], e2=cb[(size_t)2*FF],
                      e3=cb[(size_t)3*FF], e4=cb[(size_t)4*FF];
                float xx=sig_pos(e0), yy=sig_pos(e1), ob=sig_pos(e4);
                float t0=s_tv[l][0], t1=s_tv[l][1], t2v=s_tv[l][2],
                      t3v=s_tv[l][3], sc=s_tv[l][4];
                lxy += sc*sc*(bcef(xx,t0)+bcef(yy,t1));
                float d0=(e2-t2v)*sc, d1=(e3-t3v)*sc;
                lwh += 0.5f*(d0*d0+d1*d1);
                lob += -__logf(fmaxf(ob,1e-12f));
                float dx=xx-t0, dy=yy-t1, dob=ob-1.0f;
                l2  += dx*dx+dy*dy+d0*d0+d1*d1+dob*dob;
            }
        }
    }

    // ---- block reduce 5 components -> one partial slot per block ----
    float v0=lxy, v1=lwh, v2=lob, v3=lcl, v4=l2;
    #pragma unroll
    for (int off=32; off>0; off>>=1){
        v0 += __shfl_down(v0, off, 64);
        v1 += __shfl_down(v1, off, 64);
        v2 += __shfl_down(v2, off, 64);
        v3 += __shfl_down(v3, off, 64);
        v4 += __shfl_down(v4, off, 64);
    }
    if ((tid & 63) == 0){
        int w = tid >> 6;
        red[0][w]=v0; red[1][w]=v1; red[2][w]=v2; red[3][w]=v3; red[4][w]=v4;
    }
    __syncthreads();
    if (tid == 0){
        int slot = b*NBX + bxi;
        #pragma unroll
        for (int c=0; c<5; c++){
            part[c*NBLKT + slot] = red[c][0]+red[c][1]+red[c][2]+red[c][3];
        }
    }
}

// ---------------- final reduction: 1488 partials x 5 comps ----------------
__global__ __launch_bounds__(256) void fin_kernel(const float* __restrict__ part,
                                                  float* __restrict__ out)
{
    __shared__ double red[5][4];
    int tid = threadIdx.x;
    double v[5] = {0,0,0,0,0};
    for (int i = tid; i < NBLKT; i += 256){
        #pragma unroll
        for (int c=0; c<5; c++) v[c] += (double)part[c*NBLKT + i];
    }
    #pragma unroll
    for (int off=32; off>0; off>>=1){
        #pragma unroll
        for (int c=0; c<5; c++) v[c] += __shfl_down(v[c], off, 64);
    }
    if ((tid & 63) == 0){
        int w = tid >> 6;
        #pragma unroll
        for (int c=0; c<5; c++) red[c][w] = v[c];
    }
    __syncthreads();
    if (tid == 0){
        double lxy = red[0][0]+red[0][1]+red[0][2]+red[0][3];
        double lwh = red[1][0]+red[1][1]+red[1][2]+red[1][3];
        double lob = red[2][0]+red[2][1]+red[2][2]+red[2][3];
        double lcl = red[3][0]+red[3][1]+red[3][2]+red[3][3];
        double l2  = red[4][0]+red[4][1]+red[4][2]+red[4][3];
        out[0]=(float)(lxy+lwh+lob+lcl);
        out[1]=(float)lxy; out[2]=(float)lwh; out[3]=(float)lob;
        out[4]=(float)lcl; out[5]=(float)l2;
    }
}

extern "C" void kernel_launch(void* const* d_in, const int* in_sizes, int n_in,
                              void* d_out, int out_size, void* d_ws, size_t ws_size,
                              hipStream_t stream) {
    const float* x0     = (const float*)d_in[0];
    const float* x1     = (const float*)d_in[1];
    const float* x2     = (const float*)d_in[2];
    const float* labels = (const float*)d_in[3];
    float* out = (float*)d_out;

    float* part = (float*)d_ws;   // 5 * 1488 * 4 B = 29760 B

    fused_kernel<<<dim3(NBX, BB), 256, 0, stream>>>(x0, x1, x2, labels, part);
    fin_kernel<<<1, 256, 0, stream>>>(part, out);
}

// Round 4
// 27.286 us; speedup vs baseline: 13.9694x; 2.5274x over previous
//
#include <hip/hip_runtime.h>

#define BB 16
#define NL 60
#define NA 3
#define NC 80

// blocks per batch: 17(s0)+5(s1)+2(s2) cell blocks (4 cells/thread) + 3 target blocks
#define NBX0C 17
#define NBX1C 5
#define NBX2C 2
#define NBXC  (NBX0C+NBX1C+NBX2C)   // 24
#define NBX   (NBXC+3)              // 27
#define NBLKT (NBX*BB)              // 432

__device__ __constant__ float d_AW[9] = {12.f,19.f,40.f,36.f,76.f,72.f,142.f,192.f,459.f};
__device__ __constant__ float d_AH[9] = {16.f,36.f,28.f,75.f,55.f,146.f,110.f,243.f,401.f};

__device__ __forceinline__ float sig_pos(float v){ return __fdividef(1.0f, 1.0f + __expf(-v)); }
__device__ __forceinline__ float sig_neg(float v){ return __fdividef(1.0f, 1.0f + __expf(v)); }
__device__ __forceinline__ float bcef(float p, float t){
    float lp  = __logf(fmaxf(p, 1e-12f));
    float l1p = __logf(1.0f - fminf(p, 1.0f - 1e-7f));
    return -(t*lp + (1.0f - t)*l1p);
}

// ---- issue the channel loads EARLY (before prep+barrier) ----
template<int SID>
__device__ __forceinline__ bool cell_load(const float* __restrict__ raw, int xoff, int b, int tid,
        int &a, int &rembase, int &nc,
        float (&cx)[4], float (&cy)[4], float (&cw)[4], float (&ch)[4], float (&co)[4])
{
    constexpr int F  = (SID==0)?76:(SID==1)?38:19;
    constexpr int FF = F*F;
    int t = xoff*256 + tid;
    if (SID < 2){
        constexpr int NT = 3*FF/4;           // FF divisible by 4 for s0/s1
        if (t >= NT) return false;
        a = t / (FF/4);
        rembase = 4*t - a*FF;
        nc = 4;
        const float* base = raw + ((size_t)(b*(NA*85) + a*85))*FF + rembase;
        float4 q0 = *reinterpret_cast<const float4*>(base);
        float4 q1 = *reinterpret_cast<const float4*>(base +   (size_t)FF);
        float4 q2 = *reinterpret_cast<const float4*>(base + 2*(size_t)FF);
        float4 q3 = *reinterpret_cast<const float4*>(base + 3*(size_t)FF);
        float4 q4 = *reinterpret_cast<const float4*>(base + 4*(size_t)FF);
        cx[0]=q0.x; cx[1]=q0.y; cx[2]=q0.z; cx[3]=q0.w;
        cy[0]=q1.x; cy[1]=q1.y; cy[2]=q1.z; cy[3]=q1.w;
        cw[0]=q2.x; cw[1]=q2.y; cw[2]=q2.z; cw[3]=q2.w;
        ch[0]=q3.x; ch[1]=q3.y; ch[2]=q3.z; ch[3]=q3.w;
        co[0]=q4.x; co[1]=q4.y; co[2]=q4.z; co[3]=q4.w;
    } else {
        constexpr int GPA = (FF+3)/4;        // 91 groups per anchor (361 cells)
        if (t >= 3*GPA) return false;
        a = t / GPA;
        int k = t - a*GPA;
        rembase = 4*k;
        nc = (FF - rembase < 4) ? (FF - rembase) : 4;
        const float* base = raw + ((size_t)(b*(NA*85) + a*85))*FF + rembase;
        #pragma unroll
        for (int c=0;c<4;c++){
            bool v = c < nc;
            cx[c] = v ? base[c]              : 0.f;
            cy[c] = v ? base[(size_t)FF+c]   : 0.f;
            cw[c] = v ? base[2*(size_t)FF+c] : 0.f;
            ch[c] = v ? base[3*(size_t)FF+c] : 0.f;
            co[c] = v ? base[4*(size_t)FF+c] : 0.f;
        }
    }
    return true;
}

template<int SID>
__device__ __forceinline__ void cell_compute(int a, int rembase, int nc,
        const float (&cx)[4], const float (&cy)[4], const float (&cw)[4],
        const float (&ch)[4], const float (&co)[4],
        const float4* s_bx, const float* s_at3, const int* s_used, int nuse,
        float &lob, float &l2)
{
    constexpr int   F   = (SID==0)?76:(SID==1)?38:19;
    constexpr int   FF  = F*F;
    constexpr float RST = (SID==0)?0.125f:(SID==1)?0.0625f:0.03125f;
    float aw = d_AW[SID*3+a]*RST, ah = d_AH[SID*3+a]*RST;
    float plox[4],phix[4],ploy[4],phiy[4],apthr[4],lobv[4],l2v[4];
    int cellid[4];
    #pragma unroll
    for (int c=0;c<4;c++){
        int cel = rembase + c;
        int j = cel / F;                 // compile-time divisor
        int i = cel - j*F;
        float x = sig_pos(cx[c]), y = sig_pos(cy[c]);
        float pw = __expf(cw[c])*aw, ph = __expf(ch[c])*ah;
        float px = x + (float)i, py = y + (float)j;
        float hx = 0.5f*pw, hy = 0.5f*ph;
        plox[c]=px-hx; phix[c]=px+hx; ploy[c]=py-hy; phiy[c]=py+hy;
        apthr[c]=pw*ph*(1.0f/3.0f);
        float snb = sig_neg(co[c]);
        lobv[c] = -__logf(fmaxf(snb,1e-7f));
        float ob = 1.0f - snb;
        l2v[c] = ob*ob;
        cellid[c] = a*FF + cel;
    }
    bool skip0=false, skip1=false, skip2=false, skip3=false;
    #pragma unroll 2
    for (int l=0;l<NL;l++){
        float4 bb = s_bx[l];
        float thr = s_at3[l];
        float iw0 = fminf(phix[0],bb.y)-fmaxf(plox[0],bb.x);
        float ih0 = fminf(phiy[0],bb.w)-fmaxf(ploy[0],bb.z);
        float iw1 = fminf(phix[1],bb.y)-fmaxf(plox[1],bb.x);
        float ih1 = fminf(phiy[1],bb.w)-fmaxf(ploy[1],bb.z);
        float iw2 = fminf(phix[2],bb.y)-fmaxf(plox[2],bb.x);
        float ih2 = fminf(phiy[2],bb.w)-fmaxf(ploy[2],bb.z);
        float iw3 = fminf(phix[3],bb.y)-fmaxf(plox[3],bb.x);
        float ih3 = fminf(phiy[3],bb.w)-fmaxf(ploy[3],bb.z);
        skip0 = skip0 || (fmaxf(iw0,0.f)*fmaxf(ih0,0.f) > apthr[0]+thr);
        skip1 = skip1 || (fmaxf(iw1,0.f)*fmaxf(ih1,0.f) > apthr[1]+thr);
        skip2 = skip2 || (fmaxf(iw2,0.f)*fmaxf(ih2,0.f) > apthr[2]+thr);
        skip3 = skip3 || (fmaxf(iw3,0.f)*fmaxf(ih3,0.f) > apthr[3]+thr);
    }
    for (int k=0;k<nuse;k++){
        int uc = s_used[k];
        skip0 = skip0 || (uc==cellid[0]);
        skip1 = skip1 || (uc==cellid[1]);
        skip2 = skip2 || (uc==cellid[2]);
        skip3 = skip3 || (uc==cellid[3]);
    }
    if (0 < nc && !skip0){ lob += lobv[0]; l2 += l2v[0]; }
    if (1 < nc && !skip1){ lob += lobv[1]; l2 += l2v[1]; }
    if (2 < nc && !skip2){ lob += lobv[2]; l2 += l2v[2]; }
    if (3 < nc && !skip3){ lob += lobv[3]; l2 += l2v[3]; }
}

template<int SID>
__device__ __forceinline__ void target_pass(const float* __restrict__ raw, int b, int tid,
        const int* s_code, const float (*s_tv)[5],
        float &lxy, float &lwh, float &lob, float &lcl, float &l2)
{
    constexpr int F  = (SID==0)?76:(SID==1)?38:19;
    constexpr int FF = F*F;
    const int wv = tid>>6, lane = tid&63;
    int mycode = (lane < NL) ? s_code[lane] : -1;
    for (int l=wv; l<NL; l+=4){                  // wave-uniform l
        int cd = s_code[l];
        if (cd < 0) continue;
        int tcell = cd & 0xFFFFF;
        bool match = (mycode >= 0) && ((mycode & 0xFFFFF) == tcell);
        unsigned long long mask = __ballot(match);
        int last = 63 - __clzll(mask);
        if (last != l) continue;                 // single owner per cell
        unsigned long long cm0=0ull, cm1=0ull, mm=mask;
        while (mm){
            int q = __ffsll((unsigned long long)mm) - 1;
            mm &= mm - 1;
            int cc = s_code[q] >> 20;
            if (cc < 64) cm0 |= 1ull<<cc; else cm1 |= 1ull<<(cc-64);
        }
        int aa = tcell / FF, rr = tcell - aa*FF;
        const float* cb = raw + ((size_t)(b*(NA*85) + aa*85))*FF + rr;
        // hoist all loads before the transcendental block
        float p1l = cb[(size_t)(5+lane)*FF];
        float p2l = (lane < 16) ? cb[(size_t)(69+lane)*FF] : 0.f;
        float e0=0.f,e1=0.f,e2=0.f,e3=0.f,e4=0.f;
        if (lane == 0){ e0=cb[0]; e1=cb[(size_t)FF]; e2=cb[2*(size_t)FF];
                        e3=cb[3*(size_t)FF]; e4=cb[4*(size_t)FF]; }
        float p1 = sig_pos(p1l);
        float t1v = (((cm0>>lane)&1ull)!=0ull) ? 1.f : 0.f;
        lcl += bcef(p1, t1v);
        float d1 = p1 - t1v; l2 += d1*d1;
        if (lane < 16){
            float p2 = sig_pos(p2l);
            float t2v = (((cm1>>lane)&1ull)!=0ull) ? 1.f : 0.f;
            lcl += bcef(p2, t2v);
            float d2 = p2 - t2v; l2 += d2*d2;
        }
        if (lane == 0){
            float xx=sig_pos(e0), yy=sig_pos(e1), ob=sig_pos(e4);
            float t0=s_tv[l][0], t1=s_tv[l][1], t2=s_tv[l][2], t3=s_tv[l][3], sc=s_tv[l][4];
            lxy += sc*sc*(bcef(xx,t0)+bcef(yy,t1));
            float d0=(e2-t2)*sc, dd=(e3-t3)*sc;
            lwh += 0.5f*(d0*d0+dd*dd);
            lob += -__logf(fmaxf(ob,1e-12f));
            float dx=xx-t0, dy=yy-t1, dob=ob-1.f;
            l2  += dx*dx+dy*dy+d0*d0+dd*dd+dob*dob;
        }
    }
}

__global__ __launch_bounds__(256) void fused_kernel(
        const float* __restrict__ x0, const float* __restrict__ x1,
        const float* __restrict__ x2, const float* __restrict__ labels,
        float* __restrict__ part)
{
    __shared__ float4 s_bx[NL];
    __shared__ float  s_at3[NL];
    __shared__ int    s_code[NL];
    __shared__ float  s_tv[NL][5];
    __shared__ int    s_used[NL];
    __shared__ int    s_nuse;
    __shared__ float  red[5][4];

    const int tid = threadIdx.x;
    const int bxi = blockIdx.x;
    const int b   = blockIdx.y;

    int sid, xoff, tgtblk;
    if      (bxi < NBX0C)       { sid = 0; xoff = bxi;               tgtblk = 0; }
    else if (bxi < NBX0C+NBX1C) { sid = 1; xoff = bxi-NBX0C;         tgtblk = 0; }
    else if (bxi < NBXC)        { sid = 2; xoff = bxi-(NBX0C+NBX1C); tgtblk = 0; }
    else                        { sid = bxi-NBXC; xoff = 0;          tgtblk = 1; }

    const float RSTv = (sid==0)?0.125f:(sid==1)?0.0625f:0.03125f;
    const int   F    = (sid==0)?76:(sid==1)?38:19;
    const int   FF   = F*F;
    const float* raw = (sid==0)?x0:(sid==1)?x1:x2;

    // ---- issue cell loads before prep so latency hides under prep+barrier ----
    float cx[4],cy[4],cw[4],chn[4],co[4];
    int a=0, rembase=0, nc=0;
    bool active=false;
    if (!tgtblk){
        if      (sid==0) active = cell_load<0>(raw,xoff,b,tid,a,rembase,nc,cx,cy,cw,chn,co);
        else if (sid==1) active = cell_load<1>(raw,xoff,b,tid,a,rembase,nc,cx,cy,cw,chn,co);
        else             active = cell_load<2>(raw,xoff,b,tid,a,rembase,nc,cx,cy,cw,chn,co);
    }

    if (tid == 0) s_nuse = 0;
    __syncthreads();

    // ---- per-block label prep (this block's scale) ----
    if (tid < NL){
        const float* lb = labels + ((size_t)b*NL + tid)*5;
        float x1f=lb[0], y1f=lb[1], x2f=lb[2], y2f=lb[3], cl=lb[4];
        bool valid = (x1f+y1f+x2f+y2f+cl) > 0.0f;
        float tx=(x1f+x2f)*0.5f*RSTv, ty=(y1f+y2f)*0.5f*RSTv;
        float tw=(x2f-x1f)*RSTv, th=(y2f-y1f)*RSTv;
        float at=tw*th;
        float best=-1.0f; int bi=0;
        #pragma unroll
        for (int k=0;k<9;k++){
            float rw=d_AW[k]*RSTv, rh=d_AH[k]*RSTv;
            float mw=fminf(tw,rw), mh=fminf(th,rh);
            float inter=(mw>0.f && mh>0.f)? mw*mh : 0.f;
            float aiou = inter/(at + rw*rh - inter);
            if (aiou > best){ best=aiou; bi=k; }   // first-max = jnp.argmax
        }
        int bn = bi%3;
        bool use = valid && (bi/3 == sid);
        int ii=(int)tx, jj=(int)ty;
        float htw=0.5f*tw, hth=0.5f*th;
        s_bx[tid]  = make_float4(tx-htw, tx+htw, ty-hth, ty+hth);
        s_at3[tid] = at*(1.0f/3.0f);
        int cc = (bn*F + jj)*F + ii;
        s_code[tid] = use ? (cc | (((int)cl)<<20)) : -1;
        float aw=d_AW[sid*3+bn]*RSTv, ah=d_AH[sid*3+bn]*RSTv;
        s_tv[tid][0]=tx-(float)ii;
        s_tv[tid][1]=ty-(float)jj;
        s_tv[tid][2]=__logf(__fdividef(tw,aw) + 1e-16f);
        s_tv[tid][3]=__logf(__fdividef(th,ah) + 1e-16f);
        s_tv[tid][4]=sqrtf(2.0f - at/(float)FF);
        if (use){
            int p = atomicAdd(&s_nuse, 1);
            s_used[p] = cc;                       // existence-only, order-free
        }
    }
    __syncthreads();

    float lxy=0.f, lwh=0.f, lob=0.f, lcl=0.f, l2=0.f;

    if (!tgtblk){
        if (active){
            int nuse = s_nuse;
            if      (sid==0) cell_compute<0>(a,rembase,nc,cx,cy,cw,chn,co,s_bx,s_at3,s_used,nuse,lob,l2);
            else if (sid==1) cell_compute<1>(a,rembase,nc,cx,cy,cw,chn,co,s_bx,s_at3,s_used,nuse,lob,l2);
            else             cell_compute<2>(a,rembase,nc,cx,cy,cw,chn,co,s_bx,s_at3,s_used,nuse,lob,l2);
        }
    } else {
        if      (sid==0) target_pass<0>(raw,b,tid,s_code,s_tv,lxy,lwh,lob,lcl,l2);
        else if (sid==1) target_pass<1>(raw,b,tid,s_code,s_tv,lxy,lwh,lob,lcl,l2);
        else             target_pass<2>(raw,b,tid,s_code,s_tv,lxy,lwh,lob,lcl,l2);
    }

    // ---- block reduce -> one partial slot per block ----
    float v0=lxy, v1=lwh, v2=lob, v3=lcl, v4=l2;
    #pragma unroll
    for (int off=32; off>0; off>>=1){
        v0 += __shfl_down(v0, off, 64);
        v1 += __shfl_down(v1, off, 64);
        v2 += __shfl_down(v2, off, 64);
        v3 += __shfl_down(v3, off, 64);
        v4 += __shfl_down(v4, off, 64);
    }
    if ((tid & 63) == 0){
        int w = tid >> 6;
        red[0][w]=v0; red[1][w]=v1; red[2][w]=v2; red[3][w]=v3; red[4][w]=v4;
    }
    __syncthreads();
    if (tid == 0){
        int slot = b*NBX + bxi;
        #pragma unroll
        for (int c=0; c<5; c++){
            part[c*NBLKT + slot] = red[c][0]+red[c][1]+red[c][2]+red[c][3];
        }
    }
}

// ---------------- final reduction: 432 partials x 5 comps ----------------
__global__ __launch_bounds__(256) void fin_kernel(const float* __restrict__ part,
                                                  float* __restrict__ out)
{
    __shared__ double red[5][4];
    int tid = threadIdx.x;
    double v[5] = {0,0,0,0,0};
    for (int i = tid; i < NBLKT; i += 256){
        #pragma unroll
        for (int c=0; c<5; c++) v[c] += (double)part[c*NBLKT + i];
    }
    #pragma unroll
    for (int off=32; off>0; off>>=1){
        #pragma unroll
        for (int c=0; c<5; c++) v[c] += __shfl_down(v[c], off, 64);
    }
    if ((tid & 63) == 0){
        int w = tid >> 6;
        #pragma unroll
        for (int c=0; c<5; c++) red[c][w] = v[c];
    }
    __syncthreads();
    if (tid == 0){
        double lxy = red[0][0]+red[0][1]+red[0][2]+red[0][3];
        double lwh = red[1][0]+red[1][1]+red[1][2]+red[1][3];
        double lob = red[2][0]+red[2][1]+red[2][2]+red[2][3];
        double lcl = red[3][0]+red[3][1]+red[3][2]+red[3][3];
        double l2  = red[4][0]+red[4][1]+red[4][2]+red[4][3];
        out[0]=(float)(lxy+lwh+lob+lcl);
        out[1]=(float)lxy; out[2]=(float)lwh; out[3]=(float)lob;
        out[4]=(float)lcl; out[5]=(float)l2;
    }
}

extern "C" void kernel_launch(void* const* d_in, const int* in_sizes, int n_in,
                              void* d_out, int out_size, void* d_ws, size_t ws_size,
                              hipStream_t stream) {
    const float* x0     = (const float*)d_in[0];
    const float* x1     = (const float*)d_in[1];
    const float* x2     = (const float*)d_in[2];
    const float* labels = (const float*)d_in[3];
    float* out = (float*)d_out;

    float* part = (float*)d_ws;   // 5 * 432 * 4 B = 8640 B

    fused_kernel<<<dim3(NBX, BB), 256, 0, stream>>>(x0, x1, x2, labels, part);
    fin_kernel<<<1, 256, 0, stream>>>(part, out);
}